// Round 14
// baseline (332.774 us; speedup 1.0000x reference)
//
#include <hip/hip_runtime.h>
#include <hip/hip_bf16.h>
#include <hip/hip_cooperative_groups.h>
#include <stdint.h>

// GraphSAGE 2-layer encoder — atomic-free bucketed CSR build + MFMA layers.
// R23: CSR chain fused into ONE cooperative kernel (build_k): count ->
//   grid.sync -> scan2d -> grid.sync -> partition -> grid.sync -> csr_fill.
//   Each phase is the R20 block body in a grid-stride loop (no per-block
//   redundant work — R22's mistake). Removes 3 launch/drain boundaries;
//   hist2d/ep stay L2-hot across phases. Fallback: if coop launch fails,
//   run the exact R20 chain (measured 220.9us).
// R20 retained: wave __shfl_up scans; CHUNK 8192 / BSIZE 512 grain.
// Layers: R16 verbatim (8B/lane gather, (512,8), LDS-staged full-line g/r
//   stores) — proven local optimum.
// R13 retained: weights packed once (fragment-major, global, L2-resident).
// R12 retained: linearity of mean, 128B gather rows, x -> bf16 once.

namespace cg = cooperative_groups;

typedef unsigned short u16;
typedef __attribute__((ext_vector_type(8))) short short8;   // bf16x8 A/B frag
typedef __attribute__((ext_vector_type(4))) float f32x4;    // fp32x4 C/D frag

#define BSHIFT 9
#define BSIZE  512          // nodes per bucket
#define CHUNK  8192         // edges per partition block
#define NCP    256          // padded chunks-per-bucket stride (nchunk <= 256)

__device__ __forceinline__ float bf2f(u16 v) { return __uint_as_float(((uint32_t)v) << 16); }
__device__ __forceinline__ float bfu_lo(uint32_t u) { return __uint_as_float(u << 16); }
__device__ __forceinline__ float bfu_hi(uint32_t u) { return __uint_as_float(u & 0xffff0000u); }
__device__ __forceinline__ u16 f2bf(float f) {
    uint32_t u = __float_as_uint(f);
    return (u16)((u + 0x7fffu + ((u >> 16) & 1u)) >> 16);
}

// 64-lane inclusive scan in registers (Hillis-Steele via shfl_up).
__device__ __forceinline__ int wave_scan(int v) {
    int lane = threadIdx.x & 63;
#pragma unroll
    for (int d = 1; d < 64; d <<= 1) {
        int t = __shfl_up(v, d);
        if (lane >= d) v += t;
    }
    return v;
}

// 512-thread inclusive scan: wave scan + 8 wave-sum combine. 2 barriers.
__device__ __forceinline__ int block_scan512(int v, int* ws, int* ptot) {
    int tid = threadIdx.x, lane = tid & 63, wid = tid >> 6;
    int s = wave_scan(v);
    if (lane == 63) ws[wid] = s;
    __syncthreads();
    int add = 0, tot = 0;
#pragma unroll
    for (int w = 0; w < 8; w++) { int x = ws[w]; tot += x; if (w < wid) add += x; }
    if (ptot) *ptot = tot;
    __syncthreads();                    // ws safe to reuse after return
    return s + add;
}

// ---------------- fused CSR builder (cooperative) ----------------
// Phases: count -> scan2d -> partition -> csr_fill, grid.sync between.
__global__ __launch_bounds__(512) void build_k(
    const void* __restrict__ ei, int* __restrict__ hist2d,
    int* __restrict__ base2d, int* __restrict__ btot,
    unsigned* __restrict__ ep, int* __restrict__ off,
    int* __restrict__ cnt, int* __restrict__ esrc,
    int nn, int ne, int nb, int nchunk) {
    cg::grid_group grid = cg::this_grid();
    __shared__ unsigned stage[CHUNK];    // 32 KB
    __shared__ u16 ab[CHUNK];            // 16 KB
    __shared__ int hist[512], exl[512], gbase[512], lcur[512];
    __shared__ int ws[8];
    __shared__ int e64s, s_end;
    int tid = threadIdx.x;
    int G = gridDim.x;

    // e64 detect (every block, cheap)
    int samp = 0;
    if (tid < 32) {
        long long n32 = 2LL * ne;
        long long stride = n32 / 32; if (stride < 1) stride = 1;
        long long i = (long long)tid * stride; i |= 1;
        if (i >= n32) i = 1;
        samp = (((const int*)ei)[i] != 0);
    }
    unsigned long long bm = __ballot(samp);
    if (tid == 0) e64s = (bm == 0ULL) ? 1 : 0;
    __syncthreads();
    int e64 = e64s;

    // ---- Phase A: count ----
    for (int c = blockIdx.x; c < nchunk; c += G) {
        hist[tid] = 0;
        __syncthreads();
        int base = c * CHUNK;
#pragma unroll
        for (int j = 0; j < 16; j++) {
            int e = base + j * 512 + tid;
            if (e < ne) {
                int dst = e64 ? (int)((const long long*)ei)[(size_t)ne + e]
                              : ((const int*)ei)[(size_t)ne + e];
                if ((unsigned)dst < (unsigned)nn) atomicAdd(&hist[dst >> BSHIFT], 1);
            }
        }
        __syncthreads();
        for (int b = tid; b < nb; b += 512)
            hist2d[b * NCP + c] = hist[b];
        __syncthreads();
    }
    grid.sync();

    // ---- Phase B: per-bucket scan over chunks ----
    for (int b = blockIdx.x; b < nb; b += G) {
        int v = (tid < nchunk) ? hist2d[b * NCP + tid] : 0;
        int tot;
        int inc = block_scan512(v, ws, &tot);
        if (tid < nchunk) base2d[b * NCP + tid] = inc - v;
        if (tid == 0) btot[b] = tot;
        __syncthreads();
    }
    grid.sync();

    // ---- Phase C: partition ----
    for (int c = blockIdx.x; c < nchunk; c += G) {
        int base = c * CHUNK;
        hist[tid] = 0;
        __syncthreads();
        unsigned pk[16]; int bk[16];
#pragma unroll
        for (int j = 0; j < 16; j++) {
            int e = base + j * 512 + tid;
            bk[j] = -1;
            pk[j] = 0;
            if (e < ne) {
                int src, dst;
                if (e64) {
                    src = (int)((const long long*)ei)[e];
                    dst = (int)((const long long*)ei)[(size_t)ne + e];
                } else {
                    src = ((const int*)ei)[e];
                    dst = ((const int*)ei)[(size_t)ne + e];
                }
                if ((unsigned)dst < (unsigned)nn) {
                    if ((unsigned)src >= (unsigned)nn) src = 0;
                    bk[j] = dst >> BSHIFT;
                    pk[j] = (unsigned)src | ((unsigned)(dst & (BSIZE - 1)) << 17);
                    atomicAdd(&hist[bk[j]], 1);
                }
            }
        }
        __syncthreads();
        int hv = hist[tid];
        int tot;
        int inc1 = block_scan512(hv, ws, &tot);
        int ex = inc1 - hv;
        exl[tid] = ex;
        lcur[tid] = ex;
        int bv = (tid < nb) ? btot[tid] : 0;
        int inc2 = block_scan512(bv, ws, nullptr);
        int bo_t = inc2 - bv;
        gbase[tid] = (tid < nb) ? (bo_t + base2d[tid * NCP + c]) : 0;
        __syncthreads();
#pragma unroll
        for (int j = 0; j < 16; j++) {
            if (bk[j] >= 0) {
                int r = atomicAdd(&lcur[bk[j]], 1);
                stage[r] = pk[j];
                ab[r] = (u16)bk[j];
            }
        }
        __syncthreads();
        for (int j = tid; j < tot; j += 512) {
            int b = ab[j];
            ep[gbase[b] + (j - exl[b])] = stage[j];
        }
        __syncthreads();
    }
    grid.sync();

    // ---- Phase D: csr_fill ----
    for (int b = blockIdx.x; b < nb; b += G) {
        int bv = (tid < nb) ? btot[tid] : 0;
        int incb = block_scan512(bv, ws, nullptr);
        if (tid == b) s_end = incb;
        hist[tid] = 0;
        __syncthreads();
        int end = s_end;
        int beg = end - btot[b];
        for (int j = beg + tid; j < end; j += 512)
            atomicAdd(&hist[(ep[j] >> 17) & (BSIZE - 1)], 1);
        __syncthreads();
        int hv = hist[tid];
        int inc = block_scan512(hv, ws, nullptr);
        int ex = beg + inc - hv;
        lcur[tid] = ex;
        int node = b * BSIZE + tid;
        if (node < nn) { off[node] = ex; cnt[node] = hv; }
        __syncthreads();
        for (int j = beg + tid; j < end; j += 512) {
            unsigned p = ep[j];
            int r = atomicAdd(&lcur[(p >> 17) & (BSIZE - 1)], 1);
            esrc[r] = (int)(p & 0x1FFFFu);
        }
        __syncthreads();
    }
}

// ---------------- setup: probe + convert_x + count_chunks + prep_w --------
// grid = nchunk (count; 0 on the coop path) + ncvt + 4 (prep) + 1 (probe)
__global__ __launch_bounds__(512) void setup_k(
    const void* __restrict__ x, const void* __restrict__ ei,
    const void* __restrict__ W1l, const void* __restrict__ W1r,
    const void* __restrict__ b1, const void* __restrict__ W2l,
    const void* __restrict__ W2r, const void* __restrict__ b2,
    u16* __restrict__ wpk, u16* __restrict__ xb,
    int* __restrict__ hist2d, int* __restrict__ flags,
    int nn, int ne, int nb, int nchunk, int ncvt,
    int c0, int c1, int c2, int c3, int c4, int c5, int c6) {
    __shared__ int sh[512];
    __shared__ int sflag;
    int bid = blockIdx.x, tid = threadIdx.x;
    if (bid < nchunk) {
        // ---- count role (inline e64 detect) ----
        sh[tid] = 0;
        int samp = 0;
        if (tid < 32) {
            long long n32 = 2LL * ne;
            long long stride = n32 / 32; if (stride < 1) stride = 1;
            long long i = (long long)tid * stride; i |= 1;
            if (i >= n32) i = 1;
            samp = (((const int*)ei)[i] != 0);
        }
        unsigned long long m = __ballot(samp);
        if (tid == 0) sflag = (m == 0ULL) ? 1 : 0;
        __syncthreads();
        int e64 = sflag;
        int base = bid * CHUNK;
#pragma unroll
        for (int j = 0; j < 16; j++) {
            int e = base + j * 512 + tid;
            if (e < ne) {
                int dst = e64 ? (int)((const long long*)ei)[(size_t)ne + e]
                              : ((const int*)ei)[(size_t)ne + e];
                if ((unsigned)dst < (unsigned)nn) atomicAdd(&sh[dst >> BSHIFT], 1);
            }
        }
        __syncthreads();
        for (int b = tid; b < nb; b += 512)
            hist2d[b * NCP + bid] = sh[b];
    } else if (bid < nchunk + ncvt) {
        // ---- convert role (inline x-dtype detect) ----
        int samp = 0;
        if (tid < 32) {
            int C = c0; int stride = C / 32; if (stride < 1) stride = 1;
            long long i = (long long)tid * stride;
            if (i > C - 1) i = C - 1; i &= ~1LL;
            u16 v = ((const u16*)x)[i];
            int e = (v >> 7) & 0xFF;
            samp = ((e >= 0x50 && e <= 0x97) || v == 0) ? 1 : 0;
        }
        unsigned long long m = __ballot(samp);
        if (tid == 0) sflag = (__popcll(m) >= 24) ? 1 : 0;
        __syncthreads();
        if (sflag) return;   // x already bf16 — layer1 reads it directly
        int i = (bid - nchunk) * 512 + tid;
        if (i < nn * 16) {
            float4 f = ((const float4*)x)[i];
            *(ushort4*)&xb[(size_t)i * 4] =
                make_ushort4(f2bf(f.x), f2bf(f.y), f2bf(f.z), f2bf(f.w));
        }
    } else if (bid < nchunk + ncvt + 4) {
        // ---- prep role: pack one weight matrix, fragment-major ----
        int b = bid - nchunk - ncvt;
        const void* src = (b == 0) ? W1l : (b == 1) ? W1r : (b == 2) ? W2l : W2r;
        int C = (b == 0) ? c1 : (b == 1) ? c2 : (b == 2) ? c4 : c5;
        int samp = 0;
        if (tid < 32) {
            int stride = C / 32; if (stride < 1) stride = 1;
            long long i = (long long)tid * stride;
            if (i > C - 1) i = C - 1; i &= ~1LL;
            u16 v = ((const u16*)src)[i];
            int e = (v >> 7) & 0xFF;
            samp = ((e >= 0x50 && e <= 0x97) || v == 0) ? 1 : 0;
        }
        unsigned long long m = __ballot(samp);
        if (tid == 0) sflag = (__popcll(m) >= 24) ? 1 : 0;
        __syncthreads();
        int isbf = sflag;
        u16* dst = wpk + ((b >= 2) ? (16384 + (b - 2) * 8192) : 0);
        for (int i = tid; i < 2048; i += 512) {
            u16 v0, v1, v2, v3;
            if (isbf) {
                ushort4 u = ((const ushort4*)src)[i];
                v0 = u.x; v1 = u.y; v2 = u.z; v3 = u.w;
            } else {
                float4 u = ((const float4*)src)[i];
                v0 = f2bf(u.x); v1 = f2bf(u.y); v2 = f2bf(u.z); v3 = f2bf(u.w);
            }
            int k, n, k8;
            if (b <= 1) { k = i >> 5; n = (i & 31) * 4; k8 = (b == 1 ? 8 : 0) + (k >> 3); }
            else        { k = i >> 4; n = (i & 15) * 4; k8 = k >> 3; }
            int kc = k8 >> 2, q = k8 & 3, w = k & 7;
            int basei = ((n >> 4) * 4 + kc) * 512 + (q * 16 + (n & 15)) * 8 + w;
            dst[basei] = v0; dst[basei + 8] = v1; dst[basei + 16] = v2; dst[basei + 24] = v3;
        }
    } else {
        // ---- probe role: flags for layer kernels ----
        int a = tid >> 5, lane = tid & 31;
        if (tid < 8) sh[tid] = 0;
        __syncthreads();
        if (a < 7) {
            const void* ptrs[7] = {x, W1l, W1r, b1, W2l, W2r, b2};
            int cs[7] = {c0, c1, c2, c3, c4, c5, c6};
            int C = cs[a];
            int stride = C / 32; if (stride < 1) stride = 1;
            long long i = (long long)lane * stride;
            if (i > C - 1) i = C - 1;
            i &= ~1LL;
            u16 v = ((const u16*)ptrs[a])[i];
            int e = (v >> 7) & 0xFF;
            int sane = ((e >= 0x50 && e <= 0x97) || v == 0) ? 1 : 0;
            atomicAdd(&sh[a], sane);
        } else if (a == 7) {
            long long n32 = 2LL * ne;
            long long stride = n32 / 32; if (stride < 1) stride = 1;
            long long i = (long long)lane * stride; i |= 1;
            if (i >= n32) i = 1;
            int wv = ((const int*)ei)[i];
            atomicAdd(&sh[7], wv != 0 ? 1 : 0);
        }
        __syncthreads();
        if (tid < 7) flags[tid] = (sh[tid] >= 24) ? 1 : 0;
        if (tid == 7) flags[7] = (sh[7] == 0) ? 1 : 0;
    }
}

// ---------------- per-bucket scan over chunks (fallback path) ----------
__global__ __launch_bounds__(512) void scan2d(
    const int* __restrict__ hist2d, int* __restrict__ base2d,
    int* __restrict__ btot, int nchunk) {
    __shared__ int ws[8];
    int b = blockIdx.x, tid = threadIdx.x;
    int v = (tid < nchunk) ? hist2d[b * NCP + tid] : 0;
    int tot;
    int inc = block_scan512(v, ws, &tot);
    if (tid < nchunk) base2d[b * NCP + tid] = inc - v;
    if (tid == 0) btot[b] = tot;
}

// ---------------- partition (fallback path) ----------------
__global__ __launch_bounds__(512) void partition_k(
    const void* __restrict__ ei, const int* __restrict__ btot,
    const int* __restrict__ base2d,
    unsigned* __restrict__ ep, int nn, int ne, int nb) {
    __shared__ unsigned stage[CHUNK];    // 32 KB
    __shared__ u16 ab[CHUNK];            // 16 KB
    __shared__ int hist[512], exl[512], gbase[512], lcur[512];
    __shared__ int ws[8];
    __shared__ int e64s;
    int tid = threadIdx.x;
    int base = blockIdx.x * CHUNK;
    hist[tid] = 0;
    int samp = 0;
    if (tid < 32) {
        long long n32 = 2LL * ne;
        long long stride = n32 / 32; if (stride < 1) stride = 1;
        long long i = (long long)tid * stride; i |= 1;
        if (i >= n32) i = 1;
        samp = (((const int*)ei)[i] != 0);
    }
    unsigned long long bm = __ballot(samp);
    if (tid == 0) e64s = (bm == 0ULL) ? 1 : 0;
    __syncthreads();
    int e64 = e64s;
    unsigned pk[16]; int bk[16];
#pragma unroll
    for (int j = 0; j < 16; j++) {
        int e = base + j * 512 + tid;
        bk[j] = -1;
        pk[j] = 0;
        if (e < ne) {
            int src, dst;
            if (e64) {
                src = (int)((const long long*)ei)[e];
                dst = (int)((const long long*)ei)[(size_t)ne + e];
            } else {
                src = ((const int*)ei)[e];
                dst = ((const int*)ei)[(size_t)ne + e];
            }
            if ((unsigned)dst < (unsigned)nn) {
                if ((unsigned)src >= (unsigned)nn) src = 0;
                bk[j] = dst >> BSHIFT;
                pk[j] = (unsigned)src | ((unsigned)(dst & (BSIZE - 1)) << 17);
                atomicAdd(&hist[bk[j]], 1);
            }
        }
    }
    __syncthreads();
    int hv = hist[tid];
    int tot;
    int inc1 = block_scan512(hv, ws, &tot);
    int ex = inc1 - hv;
    exl[tid] = ex;
    lcur[tid] = ex;
    int bv = (tid < nb) ? btot[tid] : 0;
    int inc2 = block_scan512(bv, ws, nullptr);
    int bo_t = inc2 - bv;
    gbase[tid] = (tid < nb) ? (bo_t + base2d[tid * NCP + blockIdx.x]) : 0;
    __syncthreads();
#pragma unroll
    for (int j = 0; j < 16; j++) {
        if (bk[j] >= 0) {
            int r = atomicAdd(&lcur[bk[j]], 1);
            stage[r] = pk[j];
            ab[r] = (u16)bk[j];
        }
    }
    __syncthreads();
    for (int j = tid; j < tot; j += 512) {
        int b = ab[j];
        ep[gbase[b] + (j - exl[b])] = stage[j];
    }
}

// ---------------- per-bucket CSR finalize (fallback path) ----------------
__global__ __launch_bounds__(512) void csr_fill2(
    const unsigned* __restrict__ ep, const int* __restrict__ btot,
    int* __restrict__ off, int* __restrict__ cnt, int* __restrict__ esrc,
    int nn, int nb) {
    __shared__ int hist[BSIZE], lcur[BSIZE];
    __shared__ int ws[8];
    __shared__ int s_end;
    int b = blockIdx.x;
    int tid = threadIdx.x;
    int bv = (tid < nb) ? btot[tid] : 0;
    int incb = block_scan512(bv, ws, nullptr);
    if (tid == b) s_end = incb;
    hist[tid] = 0;
    __syncthreads();
    int end = s_end;
    int beg = end - btot[b];
    for (int j = beg + tid; j < end; j += 512)
        atomicAdd(&hist[(ep[j] >> 17) & (BSIZE - 1)], 1);
    __syncthreads();
    int hv = hist[tid];
    int inc = block_scan512(hv, ws, nullptr);
    int ex = beg + inc - hv;
    lcur[tid] = ex;
    int node = b * BSIZE + tid;
    if (node < nn) { off[node] = ex; cnt[node] = hv; }
    __syncthreads();
    for (int j = beg + tid; j < end; j += 512) {
        unsigned p = ep[j];
        int r = atomicAdd(&lcur[(p >> 17) & (BSIZE - 1)], 1);
        esrc[r] = (int)(p & 0x1FFFFu);
    }
}

// ---------------- layer 1: x-gather + W1 MFMA + fused g AND r tails ------
// R16 verbatim. 512 thr = 32 nodes x 16 lanes (8B/lane gather) = 8 waves.
__global__ __launch_bounds__(512, 8) void layer1(
    const void* __restrict__ x, const u16* __restrict__ xb,
    const int* __restrict__ esrc,
    const int* __restrict__ off, const int* __restrict__ cnt,
    const u16* __restrict__ w1g, const u16* __restrict__ w2lg,
    const u16* __restrict__ w2rg, const void* __restrict__ b1,
    u16* __restrict__ g, u16* __restrict__ rr,
    const int* __restrict__ flags, int nn) {
    __shared__ __align__(16) u16 wA[8 * 512];    // 8 KB: A-frags, then out-tiles
    __shared__ float b_s[128];
    int tid = threadIdx.x;
    int node0 = blockIdx.x * 32;

    if (tid < 128) b_s[tid] = flags[3] ? bf2f(((const u16*)b1)[tid]) : ((const float*)b1)[tid];

    int grp = tid >> 4, gl = tid & 15;
    int n = node0 + grp;
    int mtile = grp >> 4, l15m = grp & 15;
    int idx_mean = (mtile * 4 + (gl >> 3)) * 512 + (((gl >> 1) & 3) * 16 + l15m) * 8 + (gl & 1) * 4;
    int idx_x = (mtile * 4 + 2 + (gl >> 3)) * 512 + (((gl >> 1) & 3) * 16 + l15m) * 8 + (gl & 1) * 4;
    const u16* xs = flags[0] ? (const u16*)x : xb;
    if (n < nn) {
        int beg = off[n], deg = cnt[n];
        float a0 = 0.f, a1 = 0.f, a2 = 0.f, a3 = 0.f;
        int i = 0;
        const u16* xbp = xs + gl * 4;
        for (; i + 16 <= deg; i += 16) {
            ushort4 v[16];
#pragma unroll
            for (int j = 0; j < 16; j++) {
                int s0 = esrc[beg + i + j];
                v[j] = *(const ushort4*)(xbp + (size_t)s0 * 64);
            }
#pragma unroll
            for (int j = 0; j < 16; j++) {
                a0 += bf2f(v[j].x); a1 += bf2f(v[j].y);
                a2 += bf2f(v[j].z); a3 += bf2f(v[j].w);
            }
        }
        for (; i + 8 <= deg; i += 8) {
            ushort4 v[8];
#pragma unroll
            for (int j = 0; j < 8; j++) {
                int s0 = esrc[beg + i + j];
                v[j] = *(const ushort4*)(xbp + (size_t)s0 * 64);
            }
#pragma unroll
            for (int j = 0; j < 8; j++) {
                a0 += bf2f(v[j].x); a1 += bf2f(v[j].y);
                a2 += bf2f(v[j].z); a3 += bf2f(v[j].w);
            }
        }
        for (; i < deg; i++) {
            int s0 = esrc[beg + i];
            ushort4 v = *(const ushort4*)(xbp + (size_t)s0 * 64);
            a0 += bf2f(v.x); a1 += bf2f(v.y); a2 += bf2f(v.z); a3 += bf2f(v.w);
        }
        float inv = 1.0f / (float)(deg > 0 ? deg : 1);
        *(ushort4*)&wA[idx_mean] =
            make_ushort4(f2bf(a0 * inv), f2bf(a1 * inv), f2bf(a2 * inv), f2bf(a3 * inv));
        *(ushort4*)&wA[idx_x] = *(const ushort4*)(xs + (size_t)n * 64 + gl * 4);
    } else {
        *(ushort4*)&wA[idx_mean] = make_ushort4(0, 0, 0, 0);
        *(ushort4*)&wA[idx_x] = make_ushort4(0, 0, 0, 0);
    }
    __syncthreads();

    int wv = tid >> 6, lane = tid & 63;
    int l15 = lane & 15, q = lane >> 4;
    f32x4 acc0 = {0.f, 0.f, 0.f, 0.f};
    f32x4 acc1 = {0.f, 0.f, 0.f, 0.f};
#pragma unroll
    for (int kc = 0; kc < 4; kc++) {
        short8 a0 = *(const short8*)&wA[(kc) * 512 + lane * 8];
        short8 a1 = *(const short8*)&wA[(4 + kc) * 512 + lane * 8];
        short8 b  = *(const short8*)&w1g[(wv * 4 + kc) * 512 + lane * 8];
        acc0 = __builtin_amdgcn_mfma_f32_16x16x32_bf16(a0, b, acc0, 0, 0, 0);
        acc1 = __builtin_amdgcn_mfma_f32_16x16x32_bf16(a1, b, acc1, 0, 0, 0);
    }
    int nc = wv * 16 + l15;
    float bias = b_s[nc];
    u16 hv0[4], hv1[4];
#pragma unroll
    for (int r = 0; r < 4; r++) {
        hv0[r] = f2bf(fmaxf(acc0[r] + bias, 0.0f));
        hv1[r] = f2bf(fmaxf(acc1[r] + bias, 0.0f));
    }
    // ---- restage h-tile fragment-major into wA ----
    __syncthreads();                       // all waves done reading wA
    int kcg = wv >> 1;                     // nc>>5
    int qg  = ((wv & 1) << 1) | (l15 >> 3);
    int wg  = l15 & 7;
#pragma unroll
    for (int r = 0; r < 4; r++) {
        int m = q * 4 + r;
        wA[kcg * 512 + (qg * 16 + m) * 8 + wg]       = hv0[r];
        wA[(4 + kcg) * 512 + (qg * 16 + m) * 8 + wg] = hv1[r];
    }
    __syncthreads();
    // ---- g = h @ W2_l, r = h @ W2_r ----
    int mt2 = wv >> 2, nt2 = wv & 3;
    f32x4 ag = {0.f, 0.f, 0.f, 0.f};
    f32x4 ar = {0.f, 0.f, 0.f, 0.f};
#pragma unroll
    for (int kc = 0; kc < 4; kc++) {
        short8 a = *(const short8*)&wA[(mt2 * 4 + kc) * 512 + lane * 8];
        short8 bl = *(const short8*)&w2lg[(nt2 * 4 + kc) * 512 + lane * 8];
        short8 br = *(const short8*)&w2rg[(nt2 * 4 + kc) * 512 + lane * 8];
        ag = __builtin_amdgcn_mfma_f32_16x16x32_bf16(a, bl, ag, 0, 0, 0);
        ar = __builtin_amdgcn_mfma_f32_16x16x32_bf16(a, br, ar, 0, 0, 0);
    }
    // ---- stage out-tiles in LDS: g -> wA[0..2048), r -> wA[2048..4096) ----
    __syncthreads();                       // all waves done reading h frags
    int nc2 = nt2 * 16 + l15;
#pragma unroll
    for (int r = 0; r < 4; r++) {
        int m = mt2 * 16 + q * 4 + r;
        wA[m * 64 + nc2]        = f2bf(ag[r]);
        wA[2048 + m * 64 + nc2] = f2bf(ar[r]);
    }
    __syncthreads();
    // ---- coalesced full-line stores: 512 thr x 16B = 8 KB ----
    int half = tid >> 8, idx = tid & 255;
    int row = idx >> 3, seg = idx & 7;
    int nd = node0 + row;
    if (nd < nn) {
        uint4 v = *(const uint4*)&wA[half * 2048 + row * 64 + seg * 8];
        u16* dst = (half ? rr : g) + (size_t)nd * 64 + seg * 8;
        *(uint4*)dst = v;
    }
}

// ---------------- layer 2: pure gather — out = mean(g[src]) + r + b2 -----
// R16 verbatim. 512 thr = 32 nodes x 16 lanes; 8B/lane g reads.
__global__ __launch_bounds__(512, 8) void layer2(
    const u16* __restrict__ g, const u16* __restrict__ rr,
    const int* __restrict__ esrc,
    const int* __restrict__ off, const int* __restrict__ cnt,
    const void* __restrict__ b2, void* __restrict__ out,
    const int* __restrict__ flags, int nn) {
    __shared__ float b_s[64];
    int tid = threadIdx.x;
    int node0 = blockIdx.x * 32;
    int obf = flags[0];
    if (tid < 64) b_s[tid] = flags[6] ? bf2f(((const u16*)b2)[tid]) : ((const float*)b2)[tid];
    __syncthreads();

    int grp = tid >> 4, gl = tid & 15;
    int n = node0 + grp;
    if (n >= nn) return;
    int beg = off[n], deg = cnt[n];
    float a0 = 0.f, a1 = 0.f, a2 = 0.f, a3 = 0.f;
    const u16* gb = g + gl * 4;
    int i = 0;
    for (; i + 16 <= deg; i += 16) {
        uint2 v[16];
#pragma unroll
        for (int j = 0; j < 16; j++) {
            int s0 = esrc[beg + i + j];
            v[j] = *(const uint2*)(gb + (size_t)s0 * 64);
        }
#pragma unroll
        for (int j = 0; j < 16; j++) {
            a0 += bfu_lo(v[j].x); a1 += bfu_hi(v[j].x);
            a2 += bfu_lo(v[j].y); a3 += bfu_hi(v[j].y);
        }
    }
    for (; i + 8 <= deg; i += 8) {
        uint2 v[8];
#pragma unroll
        for (int j = 0; j < 8; j++) {
            int s0 = esrc[beg + i + j];
            v[j] = *(const uint2*)(gb + (size_t)s0 * 64);
        }
#pragma unroll
        for (int j = 0; j < 8; j++) {
            a0 += bfu_lo(v[j].x); a1 += bfu_hi(v[j].x);
            a2 += bfu_lo(v[j].y); a3 += bfu_hi(v[j].y);
        }
    }
    for (; i < deg; i++) {
        int s0 = esrc[beg + i];
        uint2 v = *(const uint2*)(gb + (size_t)s0 * 64);
        a0 += bfu_lo(v.x); a1 += bfu_hi(v.x);
        a2 += bfu_lo(v.y); a3 += bfu_hi(v.y);
    }
    float inv = 1.0f / (float)(deg > 0 ? deg : 1);
    uint2 rv = *(const uint2*)(rr + (size_t)n * 64 + gl * 4);
    float o0 = a0 * inv + bfu_lo(rv.x) + b_s[gl * 4 + 0];
    float o1 = a1 * inv + bfu_hi(rv.x) + b_s[gl * 4 + 1];
    float o2 = a2 * inv + bfu_lo(rv.y) + b_s[gl * 4 + 2];
    float o3 = a3 * inv + bfu_hi(rv.y) + b_s[gl * 4 + 3];
    if (obf) {
        u16* op = (u16*)out + (size_t)n * 64 + gl * 4;
        *(ushort4*)op = make_ushort4(f2bf(o0), f2bf(o1), f2bf(o2), f2bf(o3));
    } else {
        float* op = (float*)out + (size_t)n * 64 + gl * 4;
        *(float4*)op = make_float4(o0, o1, o2, o3);
    }
}

// ---------------- fallback ----------------
__global__ __launch_bounds__(256) void zero_out_k(u16* __restrict__ out, int n) {
    int i = blockIdx.x * 256 + threadIdx.x;
    if (i < n) out[i] = 0;
}

extern "C" void kernel_launch(void* const* d_in, const int* in_sizes, int n_in,
                              void* d_out, int out_size, void* d_ws, size_t ws_size,
                              hipStream_t stream) {
    const void* x   = d_in[0];
    const void* ei  = d_in[1];
    const void* W1l = d_in[2];
    const void* W1r = d_in[3];
    const void* b1  = d_in[4];
    const void* W2l = d_in[5];
    const void* W2r = d_in[6];
    const void* b2  = d_in[7];

    int nn = in_sizes[0] / 64;
    int ne = in_sizes[1] / 2;
    int nb = (nn + BSIZE - 1) / BSIZE;
    int nchunk = (ne + CHUNK - 1) / CHUNK;

    auto al = [](size_t v) { return (v + 255) & ~(size_t)255; };
    size_t o_flags = 0;
    size_t o_btot  = 256;                              // 512 ints
    size_t o_wpk   = al(o_btot + 512 * 4);             // 64 KB packed weights
    size_t o_cnt   = al(o_wpk + 65536);
    size_t o_off   = al(o_cnt + (size_t)nn * 4);
    size_t o_esrc  = al(o_off + (size_t)nn * 4);
    size_t o_r     = al(o_esrc + (size_t)ne * 4);      // r = h@W2r, bf16 [nn,64]
    size_t o_xb    = al(o_r + (size_t)nn * 64 * 2);    // x as bf16
    size_t o_g     = al(o_xb + (size_t)nn * 64 * 2);   // g = h@W2l, bf16 [nn,64]
    size_t ws_req  = o_g + (size_t)nn * 64 * 2;

    // overlays inside the r region (all dead before layer1 writes r):
    size_t o_ep   = o_r;                               // ne*4 B
    size_t o_h2d  = al(o_ep + (size_t)ne * 4);         // nb*NCP*4
    size_t o_b2d  = al(o_h2d + (size_t)512 * NCP * 4); // nb*NCP*4
    size_t ov_end = o_b2d + (size_t)512 * NCP * 4;

    bool ok = ws_size >= ws_req && nb >= 1 && nb <= 512 && nn <= 131072 &&
              nchunk <= NCP && ov_end <= o_xb;
    if (!ok) {
        zero_out_k<<<(out_size + 255) / 256, 256, 0, stream>>>((u16*)d_out, out_size);
        return;
    }

    char* ws = (char*)d_ws;
    int* flags  = (int*)(ws + o_flags);
    int* btot   = (int*)(ws + o_btot);
    u16* wpk    = (u16*)(ws + o_wpk);
    int* cnt    = (int*)(ws + o_cnt);
    int* off    = (int*)(ws + o_off);
    int* esrc   = (int*)(ws + o_esrc);
    u16* rbuf   = (u16*)(ws + o_r);
    u16* xb     = (u16*)(ws + o_xb);
    u16* gbuf   = (u16*)(ws + o_g);
    unsigned* ep = (unsigned*)(ws + o_ep);
    int* hist2d = (int*)(ws + o_h2d);
    int* base2d = (int*)(ws + o_b2d);

    int ncvt = (nn * 16 + 511) / 512;

    // ---- try fused cooperative CSR build (one launch replaces four) ----
    const void* a_ei = ei; int* a_h2d = hist2d; int* a_b2d = base2d;
    int* a_btot = btot; unsigned* a_ep = ep; int* a_off = off;
    int* a_cnt = cnt; int* a_esrc = esrc;
    int a_nn = nn, a_ne = ne, a_nb = nb, a_nchunk = nchunk;
    void* cargs[] = {&a_ei, &a_h2d, &a_b2d, &a_btot, &a_ep, &a_off,
                     &a_cnt, &a_esrc, &a_nn, &a_ne, &a_nb, &a_nchunk};
    hipError_t cerr = hipLaunchCooperativeKernel(
        (const void*)build_k, dim3(256), dim3(512), cargs, 0, stream);

    if (cerr == hipSuccess) {
        // small setup: probe/convert/prep only (count handled by build_k)
        setup_k<<<ncvt + 5, 512, 0, stream>>>(
            x, ei, W1l, W1r, b1, W2l, W2r, b2, wpk, xb, hist2d, flags,
            nn, ne, nb, /*nchunk=*/0, ncvt,
            in_sizes[0], in_sizes[2], in_sizes[3], in_sizes[4],
            in_sizes[5], in_sizes[6], in_sizes[7]);
    } else {
        // fallback: exact R20 chain
        setup_k<<<nchunk + ncvt + 5, 512, 0, stream>>>(
            x, ei, W1l, W1r, b1, W2l, W2r, b2, wpk, xb, hist2d, flags,
            nn, ne, nb, nchunk, ncvt,
            in_sizes[0], in_sizes[2], in_sizes[3], in_sizes[4],
            in_sizes[5], in_sizes[6], in_sizes[7]);
        scan2d<<<nb, 512, 0, stream>>>(hist2d, base2d, btot, nchunk);
        partition_k<<<nchunk, 512, 0, stream>>>(ei, btot, base2d, ep, nn, ne, nb);
        csr_fill2<<<nb, 512, 0, stream>>>(ep, btot, off, cnt, esrc, nn, nb);
    }

    int lb = (nn + 31) / 32;
    layer1<<<lb, 512, 0, stream>>>(x, xb, esrc, off, cnt,
                                   wpk, wpk + 16384, wpk + 24576, b1,
                                   gbuf, rbuf, flags, nn);
    layer2<<<lb, 512, 0, stream>>>(gbuf, rbuf, esrc, off, cnt, b2, d_out, flags, nn);
}

// Round 15
// 220.461 us; speedup vs baseline: 1.5094x; 1.5094x over previous
//
#include <hip/hip_runtime.h>
#include <hip/hip_bf16.h>
#include <stdint.h>

// GraphSAGE 2-layer encoder — atomic-free bucketed CSR build + MFMA layers.
// R24: direct-write partition. R23 proved the chain is a latency-chain at
//   1 block/CU (build_k: 118us, FETCH 10MB, VALUBusy 2.3%, occ 22% — the
//   56KB LDS stage capped residency). partition_k now seeds per-bucket
//   cursors with the GLOBAL base (bo[b]+base2d[b][chunk]) and writes ep
//   directly via LDS atomic rank — stage/ab/hist/exl deleted (56KB -> 2KB
//   LDS -> 4 blocks/CU), hist pass + scan + compaction loop gone. Final
//   positions identical (order within node already nondeterministic).
// R20 retained: 4-kernel chain, wave __shfl_up scans, CHUNK 8192/BSIZE 512.
// Layers: R16 verbatim (8B/lane gather, (512,8), LDS-staged full-line g/r
//   stores) — proven local optimum.
// R13 retained: weights packed once (fragment-major, global, L2-resident).
// R12 retained: linearity of mean, 128B gather rows, x -> bf16 once.

typedef unsigned short u16;
typedef __attribute__((ext_vector_type(8))) short short8;   // bf16x8 A/B frag
typedef __attribute__((ext_vector_type(4))) float f32x4;    // fp32x4 C/D frag

#define BSHIFT 9
#define BSIZE  512          // nodes per bucket
#define CHUNK  8192         // edges per partition block
#define NCP    256          // padded chunks-per-bucket stride (nchunk <= 256)

__device__ __forceinline__ float bf2f(u16 v) { return __uint_as_float(((uint32_t)v) << 16); }
__device__ __forceinline__ float bfu_lo(uint32_t u) { return __uint_as_float(u << 16); }
__device__ __forceinline__ float bfu_hi(uint32_t u) { return __uint_as_float(u & 0xffff0000u); }
__device__ __forceinline__ u16 f2bf(float f) {
    uint32_t u = __float_as_uint(f);
    return (u16)((u + 0x7fffu + ((u >> 16) & 1u)) >> 16);
}

// 64-lane inclusive scan in registers (Hillis-Steele via shfl_up).
__device__ __forceinline__ int wave_scan(int v) {
    int lane = threadIdx.x & 63;
#pragma unroll
    for (int d = 1; d < 64; d <<= 1) {
        int t = __shfl_up(v, d);
        if (lane >= d) v += t;
    }
    return v;
}

// 512-thread inclusive scan: wave scan + 8 wave-sum combine. 2 barriers.
__device__ __forceinline__ int block_scan512(int v, int* ws, int* ptot) {
    int tid = threadIdx.x, lane = tid & 63, wid = tid >> 6;
    int s = wave_scan(v);
    if (lane == 63) ws[wid] = s;
    __syncthreads();
    int add = 0, tot = 0;
#pragma unroll
    for (int w = 0; w < 8; w++) { int x = ws[w]; tot += x; if (w < wid) add += x; }
    if (ptot) *ptot = tot;
    __syncthreads();                    // ws safe to reuse after return
    return s + add;
}

// 256-thread variant (4 waves).
__device__ __forceinline__ int block_scan256(int v, int* ws, int* ptot) {
    int tid = threadIdx.x, lane = tid & 63, wid = tid >> 6;
    int s = wave_scan(v);
    if (lane == 63) ws[wid] = s;
    __syncthreads();
    int add = 0, tot = 0;
#pragma unroll
    for (int w = 0; w < 4; w++) { int x = ws[w]; tot += x; if (w < wid) add += x; }
    if (ptot) *ptot = tot;
    __syncthreads();
    return s + add;
}

// ---------------- setup: probe + convert_x + count_chunks + prep_w --------
// grid = nchunk (count) + ncvt (convert) + 4 (prep) + 1 (probe flags)
__global__ __launch_bounds__(512) void setup_k(
    const void* __restrict__ x, const void* __restrict__ ei,
    const void* __restrict__ W1l, const void* __restrict__ W1r,
    const void* __restrict__ b1, const void* __restrict__ W2l,
    const void* __restrict__ W2r, const void* __restrict__ b2,
    u16* __restrict__ wpk, u16* __restrict__ xb,
    int* __restrict__ hist2d, int* __restrict__ flags,
    int nn, int ne, int nb, int nchunk, int ncvt,
    int c0, int c1, int c2, int c3, int c4, int c5, int c6) {
    __shared__ int sh[512];
    __shared__ int sflag;
    int bid = blockIdx.x, tid = threadIdx.x;
    if (bid < nchunk) {
        // ---- count role (inline e64 detect) ----
        sh[tid] = 0;
        int samp = 0;
        if (tid < 32) {
            long long n32 = 2LL * ne;
            long long stride = n32 / 32; if (stride < 1) stride = 1;
            long long i = (long long)tid * stride; i |= 1;
            if (i >= n32) i = 1;
            samp = (((const int*)ei)[i] != 0);
        }
        unsigned long long m = __ballot(samp);
        if (tid == 0) sflag = (m == 0ULL) ? 1 : 0;
        __syncthreads();
        int e64 = sflag;
        int base = bid * CHUNK;
#pragma unroll
        for (int j = 0; j < 16; j++) {
            int e = base + j * 512 + tid;
            if (e < ne) {
                int dst = e64 ? (int)((const long long*)ei)[(size_t)ne + e]
                              : ((const int*)ei)[(size_t)ne + e];
                if ((unsigned)dst < (unsigned)nn) atomicAdd(&sh[dst >> BSHIFT], 1);
            }
        }
        __syncthreads();
        for (int b = tid; b < nb; b += 512)
            hist2d[b * NCP + bid] = sh[b];
    } else if (bid < nchunk + ncvt) {
        // ---- convert role (inline x-dtype detect) ----
        int samp = 0;
        if (tid < 32) {
            int C = c0; int stride = C / 32; if (stride < 1) stride = 1;
            long long i = (long long)tid * stride;
            if (i > C - 1) i = C - 1; i &= ~1LL;
            u16 v = ((const u16*)x)[i];
            int e = (v >> 7) & 0xFF;
            samp = ((e >= 0x50 && e <= 0x97) || v == 0) ? 1 : 0;
        }
        unsigned long long m = __ballot(samp);
        if (tid == 0) sflag = (__popcll(m) >= 24) ? 1 : 0;
        __syncthreads();
        if (sflag) return;   // x already bf16 — layer1 reads it directly
        int i = (bid - nchunk) * 512 + tid;
        if (i < nn * 16) {
            float4 f = ((const float4*)x)[i];
            *(ushort4*)&xb[(size_t)i * 4] =
                make_ushort4(f2bf(f.x), f2bf(f.y), f2bf(f.z), f2bf(f.w));
        }
    } else if (bid < nchunk + ncvt + 4) {
        // ---- prep role: pack one weight matrix, fragment-major ----
        int b = bid - nchunk - ncvt;
        const void* src = (b == 0) ? W1l : (b == 1) ? W1r : (b == 2) ? W2l : W2r;
        int C = (b == 0) ? c1 : (b == 1) ? c2 : (b == 2) ? c4 : c5;
        int samp = 0;
        if (tid < 32) {
            int stride = C / 32; if (stride < 1) stride = 1;
            long long i = (long long)tid * stride;
            if (i > C - 1) i = C - 1; i &= ~1LL;
            u16 v = ((const u16*)src)[i];
            int e = (v >> 7) & 0xFF;
            samp = ((e >= 0x50 && e <= 0x97) || v == 0) ? 1 : 0;
        }
        unsigned long long m = __ballot(samp);
        if (tid == 0) sflag = (__popcll(m) >= 24) ? 1 : 0;
        __syncthreads();
        int isbf = sflag;
        u16* dst = wpk + ((b >= 2) ? (16384 + (b - 2) * 8192) : 0);
        for (int i = tid; i < 2048; i += 512) {
            u16 v0, v1, v2, v3;
            if (isbf) {
                ushort4 u = ((const ushort4*)src)[i];
                v0 = u.x; v1 = u.y; v2 = u.z; v3 = u.w;
            } else {
                float4 u = ((const float4*)src)[i];
                v0 = f2bf(u.x); v1 = f2bf(u.y); v2 = f2bf(u.z); v3 = f2bf(u.w);
            }
            int k, n, k8;
            if (b <= 1) { k = i >> 5; n = (i & 31) * 4; k8 = (b == 1 ? 8 : 0) + (k >> 3); }
            else        { k = i >> 4; n = (i & 15) * 4; k8 = k >> 3; }
            int kc = k8 >> 2, q = k8 & 3, w = k & 7;
            int basei = ((n >> 4) * 4 + kc) * 512 + (q * 16 + (n & 15)) * 8 + w;
            dst[basei] = v0; dst[basei + 8] = v1; dst[basei + 16] = v2; dst[basei + 24] = v3;
        }
    } else {
        // ---- probe role: flags for layer kernels ----
        int a = tid >> 5, lane = tid & 31;
        if (tid < 8) sh[tid] = 0;
        __syncthreads();
        if (a < 7) {
            const void* ptrs[7] = {x, W1l, W1r, b1, W2l, W2r, b2};
            int cs[7] = {c0, c1, c2, c3, c4, c5, c6};
            int C = cs[a];
            int stride = C / 32; if (stride < 1) stride = 1;
            long long i = (long long)lane * stride;
            if (i > C - 1) i = C - 1;
            i &= ~1LL;
            u16 v = ((const u16*)ptrs[a])[i];
            int e = (v >> 7) & 0xFF;
            int sane = ((e >= 0x50 && e <= 0x97) || v == 0) ? 1 : 0;
            atomicAdd(&sh[a], sane);
        } else if (a == 7) {
            long long n32 = 2LL * ne;
            long long stride = n32 / 32; if (stride < 1) stride = 1;
            long long i = (long long)lane * stride; i |= 1;
            if (i >= n32) i = 1;
            int wv = ((const int*)ei)[i];
            atomicAdd(&sh[7], wv != 0 ? 1 : 0);
        }
        __syncthreads();
        if (tid < 7) flags[tid] = (sh[tid] >= 24) ? 1 : 0;
        if (tid == 7) flags[7] = (sh[7] == 0) ? 1 : 0;
    }
}

// ---------------- per-bucket scan over chunks (wave scan, 2 barriers) ----
__global__ __launch_bounds__(256) void scan2d(
    const int* __restrict__ hist2d, int* __restrict__ base2d,
    int* __restrict__ btot, int nchunk) {
    __shared__ int ws[4];
    int b = blockIdx.x, tid = threadIdx.x;
    int v = (tid < nchunk) ? hist2d[b * NCP + tid] : 0;
    int tot;
    int inc = block_scan256(v, ws, &tot);
    if (tid < nchunk) base2d[b * NCP + tid] = inc - v;
    if (tid == 0) btot[b] = tot;
}

// ---------------- partition: DIRECT global write via LDS cursors ---------
// lcur[b] seeded with global base (bo[b] + base2d[b][chunk]); each edge
// writes ep[atomicAdd(&lcur[bk],1)] directly. ~2KB LDS -> 4 blocks/CU.
__global__ __launch_bounds__(512) void partition_k(
    const void* __restrict__ ei, const int* __restrict__ btot,
    const int* __restrict__ base2d,
    unsigned* __restrict__ ep, int nn, int ne, int nb) {
    __shared__ int lcur[512];
    __shared__ int ws[8];
    __shared__ int e64s;
    int tid = threadIdx.x;
    int base = blockIdx.x * CHUNK;
    int samp = 0;
    if (tid < 32) {
        long long n32 = 2LL * ne;
        long long stride = n32 / 32; if (stride < 1) stride = 1;
        long long i = (long long)tid * stride; i |= 1;
        if (i >= n32) i = 1;
        samp = (((const int*)ei)[i] != 0);
    }
    unsigned long long bm = __ballot(samp);
    if (tid == 0) e64s = (bm == 0ULL) ? 1 : 0;
    __syncthreads();
    int e64 = e64s;
    // bucket-offset scan + seed cursors with global bases
    int bv = (tid < nb) ? btot[tid] : 0;
    int inc = block_scan512(bv, ws, nullptr);
    int bo_t = inc - bv;
    lcur[tid] = (tid < nb) ? (bo_t + base2d[tid * NCP + blockIdx.x]) : 0;
    __syncthreads();
#pragma unroll
    for (int j = 0; j < 16; j++) {
        int e = base + j * 512 + tid;
        if (e < ne) {
            int src, dst;
            if (e64) {
                src = (int)((const long long*)ei)[e];
                dst = (int)((const long long*)ei)[(size_t)ne + e];
            } else {
                src = ((const int*)ei)[e];
                dst = ((const int*)ei)[(size_t)ne + e];
            }
            if ((unsigned)dst < (unsigned)nn) {
                if ((unsigned)src >= (unsigned)nn) src = 0;
                int bk = dst >> BSHIFT;
                unsigned pk = (unsigned)src | ((unsigned)(dst & (BSIZE - 1)) << 17);
                int r = atomicAdd(&lcur[bk], 1);
                ep[r] = pk;
            }
        }
    }
}

// ---------------- per-bucket CSR finalize (wave scans) ----------------
__global__ __launch_bounds__(512) void csr_fill2(
    const unsigned* __restrict__ ep, const int* __restrict__ btot,
    int* __restrict__ off, int* __restrict__ cnt, int* __restrict__ esrc,
    int nn, int nb) {
    __shared__ int hist[BSIZE], lcur[BSIZE];
    __shared__ int ws[8];
    __shared__ int s_end;
    int b = blockIdx.x;
    int tid = threadIdx.x;
    // bucket-offset scan: need inclusive prefix at index b
    int bv = (tid < nb) ? btot[tid] : 0;
    int incb = block_scan512(bv, ws, nullptr);
    if (tid == b) s_end = incb;
    hist[tid] = 0;
    __syncthreads();
    int end = s_end;
    int beg = end - btot[b];
    for (int j = beg + tid; j < end; j += 512)
        atomicAdd(&hist[(ep[j] >> 17) & (BSIZE - 1)], 1);
    __syncthreads();
    int hv = hist[tid];
    int inc = block_scan512(hv, ws, nullptr);
    int ex = beg + inc - hv;
    lcur[tid] = ex;
    int node = b * BSIZE + tid;
    if (node < nn) { off[node] = ex; cnt[node] = hv; }
    __syncthreads();
    for (int j = beg + tid; j < end; j += 512) {
        unsigned p = ep[j];
        int r = atomicAdd(&lcur[(p >> 17) & (BSIZE - 1)], 1);
        esrc[r] = (int)(p & 0x1FFFFu);
    }
}

// ---------------- layer 1: x-gather + W1 MFMA + fused g AND r tails ------
// R16 verbatim. 512 thr = 32 nodes x 16 lanes (8B/lane gather) = 8 waves.
// Tile M=32,N=128,K=128. h never stored: h-tile restaged fragment-major
// into wA, then g = h @ W2_l and r = h @ W2_r (4+4 MFMAs/wave).
// OUT: tiles staged in LDS (reuse wA) -> full-line 16B/lane stores.
__global__ __launch_bounds__(512, 8) void layer1(
    const void* __restrict__ x, const u16* __restrict__ xb,
    const int* __restrict__ esrc,
    const int* __restrict__ off, const int* __restrict__ cnt,
    const u16* __restrict__ w1g, const u16* __restrict__ w2lg,
    const u16* __restrict__ w2rg, const void* __restrict__ b1,
    u16* __restrict__ g, u16* __restrict__ rr,
    const int* __restrict__ flags, int nn) {
    __shared__ __align__(16) u16 wA[8 * 512];    // 8 KB: A-frags, then out-tiles
    __shared__ float b_s[128];
    int tid = threadIdx.x;
    int node0 = blockIdx.x * 32;

    if (tid < 128) b_s[tid] = flags[3] ? bf2f(((const u16*)b1)[tid]) : ((const float*)b1)[tid];

    int grp = tid >> 4, gl = tid & 15;
    int n = node0 + grp;
    int mtile = grp >> 4, l15m = grp & 15;
    int idx_mean = (mtile * 4 + (gl >> 3)) * 512 + (((gl >> 1) & 3) * 16 + l15m) * 8 + (gl & 1) * 4;
    int idx_x = (mtile * 4 + 2 + (gl >> 3)) * 512 + (((gl >> 1) & 3) * 16 + l15m) * 8 + (gl & 1) * 4;
    const u16* xs = flags[0] ? (const u16*)x : xb;
    if (n < nn) {
        int beg = off[n], deg = cnt[n];
        float a0 = 0.f, a1 = 0.f, a2 = 0.f, a3 = 0.f;
        int i = 0;
        const u16* xbp = xs + gl * 4;
        for (; i + 16 <= deg; i += 16) {
            ushort4 v[16];
#pragma unroll
            for (int j = 0; j < 16; j++) {
                int s0 = esrc[beg + i + j];
                v[j] = *(const ushort4*)(xbp + (size_t)s0 * 64);
            }
#pragma unroll
            for (int j = 0; j < 16; j++) {
                a0 += bf2f(v[j].x); a1 += bf2f(v[j].y);
                a2 += bf2f(v[j].z); a3 += bf2f(v[j].w);
            }
        }
        for (; i + 8 <= deg; i += 8) {
            ushort4 v[8];
#pragma unroll
            for (int j = 0; j < 8; j++) {
                int s0 = esrc[beg + i + j];
                v[j] = *(const ushort4*)(xbp + (size_t)s0 * 64);
            }
#pragma unroll
            for (int j = 0; j < 8; j++) {
                a0 += bf2f(v[j].x); a1 += bf2f(v[j].y);
                a2 += bf2f(v[j].z); a3 += bf2f(v[j].w);
            }
        }
        for (; i < deg; i++) {
            int s0 = esrc[beg + i];
            ushort4 v = *(const ushort4*)(xbp + (size_t)s0 * 64);
            a0 += bf2f(v.x); a1 += bf2f(v.y); a2 += bf2f(v.z); a3 += bf2f(v.w);
        }
        float inv = 1.0f / (float)(deg > 0 ? deg : 1);
        *(ushort4*)&wA[idx_mean] =
            make_ushort4(f2bf(a0 * inv), f2bf(a1 * inv), f2bf(a2 * inv), f2bf(a3 * inv));
        *(ushort4*)&wA[idx_x] = *(const ushort4*)(xs + (size_t)n * 64 + gl * 4);
    } else {
        *(ushort4*)&wA[idx_mean] = make_ushort4(0, 0, 0, 0);
        *(ushort4*)&wA[idx_x] = make_ushort4(0, 0, 0, 0);
    }
    __syncthreads();

    int wv = tid >> 6, lane = tid & 63;
    int l15 = lane & 15, q = lane >> 4;
    f32x4 acc0 = {0.f, 0.f, 0.f, 0.f};
    f32x4 acc1 = {0.f, 0.f, 0.f, 0.f};
#pragma unroll
    for (int kc = 0; kc < 4; kc++) {
        short8 a0 = *(const short8*)&wA[(kc) * 512 + lane * 8];
        short8 a1 = *(const short8*)&wA[(4 + kc) * 512 + lane * 8];
        short8 b  = *(const short8*)&w1g[(wv * 4 + kc) * 512 + lane * 8];
        acc0 = __builtin_amdgcn_mfma_f32_16x16x32_bf16(a0, b, acc0, 0, 0, 0);
        acc1 = __builtin_amdgcn_mfma_f32_16x16x32_bf16(a1, b, acc1, 0, 0, 0);
    }
    int nc = wv * 16 + l15;
    float bias = b_s[nc];
    u16 hv0[4], hv1[4];
#pragma unroll
    for (int r = 0; r < 4; r++) {
        hv0[r] = f2bf(fmaxf(acc0[r] + bias, 0.0f));
        hv1[r] = f2bf(fmaxf(acc1[r] + bias, 0.0f));
    }
    // ---- restage h-tile fragment-major into wA ----
    __syncthreads();                       // all waves done reading wA
    int kcg = wv >> 1;                     // nc>>5
    int qg  = ((wv & 1) << 1) | (l15 >> 3);
    int wg  = l15 & 7;
#pragma unroll
    for (int r = 0; r < 4; r++) {
        int m = q * 4 + r;
        wA[kcg * 512 + (qg * 16 + m) * 8 + wg]       = hv0[r];
        wA[(4 + kcg) * 512 + (qg * 16 + m) * 8 + wg] = hv1[r];
    }
    __syncthreads();
    // ---- g = h @ W2_l, r = h @ W2_r ----
    int mt2 = wv >> 2, nt2 = wv & 3;
    f32x4 ag = {0.f, 0.f, 0.f, 0.f};
    f32x4 ar = {0.f, 0.f, 0.f, 0.f};
#pragma unroll
    for (int kc = 0; kc < 4; kc++) {
        short8 a = *(const short8*)&wA[(mt2 * 4 + kc) * 512 + lane * 8];
        short8 bl = *(const short8*)&w2lg[(nt2 * 4 + kc) * 512 + lane * 8];
        short8 br = *(const short8*)&w2rg[(nt2 * 4 + kc) * 512 + lane * 8];
        ag = __builtin_amdgcn_mfma_f32_16x16x32_bf16(a, bl, ag, 0, 0, 0);
        ar = __builtin_amdgcn_mfma_f32_16x16x32_bf16(a, br, ar, 0, 0, 0);
    }
    // ---- stage out-tiles in LDS: g -> wA[0..2048), r -> wA[2048..4096) ----
    __syncthreads();                       // all waves done reading h frags
    int nc2 = nt2 * 16 + l15;
#pragma unroll
    for (int r = 0; r < 4; r++) {
        int m = mt2 * 16 + q * 4 + r;
        wA[m * 64 + nc2]        = f2bf(ag[r]);
        wA[2048 + m * 64 + nc2] = f2bf(ar[r]);
    }
    __syncthreads();
    // ---- coalesced full-line stores: 512 thr x 16B = 8 KB ----
    int half = tid >> 8, idx = tid & 255;
    int row = idx >> 3, seg = idx & 7;
    int nd = node0 + row;
    if (nd < nn) {
        uint4 v = *(const uint4*)&wA[half * 2048 + row * 64 + seg * 8];
        u16* dst = (half ? rr : g) + (size_t)nd * 64 + seg * 8;
        *(uint4*)dst = v;
    }
}

// ---------------- layer 2: pure gather — out = mean(g[src]) + r + b2 -----
// R16 verbatim. 512 thr = 32 nodes x 16 lanes; 8B/lane g reads.
__global__ __launch_bounds__(512, 8) void layer2(
    const u16* __restrict__ g, const u16* __restrict__ rr,
    const int* __restrict__ esrc,
    const int* __restrict__ off, const int* __restrict__ cnt,
    const void* __restrict__ b2, void* __restrict__ out,
    const int* __restrict__ flags, int nn) {
    __shared__ float b_s[64];
    int tid = threadIdx.x;
    int node0 = blockIdx.x * 32;
    int obf = flags[0];
    if (tid < 64) b_s[tid] = flags[6] ? bf2f(((const u16*)b2)[tid]) : ((const float*)b2)[tid];
    __syncthreads();

    int grp = tid >> 4, gl = tid & 15;
    int n = node0 + grp;
    if (n >= nn) return;
    int beg = off[n], deg = cnt[n];
    float a0 = 0.f, a1 = 0.f, a2 = 0.f, a3 = 0.f;
    const u16* gb = g + gl * 4;
    int i = 0;
    for (; i + 16 <= deg; i += 16) {
        uint2 v[16];
#pragma unroll
        for (int j = 0; j < 16; j++) {
            int s0 = esrc[beg + i + j];
            v[j] = *(const uint2*)(gb + (size_t)s0 * 64);
        }
#pragma unroll
        for (int j = 0; j < 16; j++) {
            a0 += bfu_lo(v[j].x); a1 += bfu_hi(v[j].x);
            a2 += bfu_lo(v[j].y); a3 += bfu_hi(v[j].y);
        }
    }
    for (; i + 8 <= deg; i += 8) {
        uint2 v[8];
#pragma unroll
        for (int j = 0; j < 8; j++) {
            int s0 = esrc[beg + i + j];
            v[j] = *(const uint2*)(gb + (size_t)s0 * 64);
        }
#pragma unroll
        for (int j = 0; j < 8; j++) {
            a0 += bfu_lo(v[j].x); a1 += bfu_hi(v[j].x);
            a2 += bfu_lo(v[j].y); a3 += bfu_hi(v[j].y);
        }
    }
    for (; i < deg; i++) {
        int s0 = esrc[beg + i];
        uint2 v = *(const uint2*)(gb + (size_t)s0 * 64);
        a0 += bfu_lo(v.x); a1 += bfu_hi(v.x);
        a2 += bfu_lo(v.y); a3 += bfu_hi(v.y);
    }
    float inv = 1.0f / (float)(deg > 0 ? deg : 1);
    uint2 rv = *(const uint2*)(rr + (size_t)n * 64 + gl * 4);
    float o0 = a0 * inv + bfu_lo(rv.x) + b_s[gl * 4 + 0];
    float o1 = a1 * inv + bfu_hi(rv.x) + b_s[gl * 4 + 1];
    float o2 = a2 * inv + bfu_lo(rv.y) + b_s[gl * 4 + 2];
    float o3 = a3 * inv + bfu_hi(rv.y) + b_s[gl * 4 + 3];
    if (obf) {
        u16* op = (u16*)out + (size_t)n * 64 + gl * 4;
        *(ushort4*)op = make_ushort4(f2bf(o0), f2bf(o1), f2bf(o2), f2bf(o3));
    } else {
        float* op = (float*)out + (size_t)n * 64 + gl * 4;
        *(float4*)op = make_float4(o0, o1, o2, o3);
    }
}

// ---------------- fallback ----------------
__global__ __launch_bounds__(256) void zero_out_k(u16* __restrict__ out, int n) {
    int i = blockIdx.x * 256 + threadIdx.x;
    if (i < n) out[i] = 0;
}

extern "C" void kernel_launch(void* const* d_in, const int* in_sizes, int n_in,
                              void* d_out, int out_size, void* d_ws, size_t ws_size,
                              hipStream_t stream) {
    const void* x   = d_in[0];
    const void* ei  = d_in[1];
    const void* W1l = d_in[2];
    const void* W1r = d_in[3];
    const void* b1  = d_in[4];
    const void* W2l = d_in[5];
    const void* W2r = d_in[6];
    const void* b2  = d_in[7];

    int nn = in_sizes[0] / 64;
    int ne = in_sizes[1] / 2;
    int nb = (nn + BSIZE - 1) / BSIZE;
    int nchunk = (ne + CHUNK - 1) / CHUNK;

    auto al = [](size_t v) { return (v + 255) & ~(size_t)255; };
    size_t o_flags = 0;
    size_t o_btot  = 256;                              // 512 ints
    size_t o_wpk   = al(o_btot + 512 * 4);             // 64 KB packed weights
    size_t o_cnt   = al(o_wpk + 65536);
    size_t o_off   = al(o_cnt + (size_t)nn * 4);
    size_t o_esrc  = al(o_off + (size_t)nn * 4);
    size_t o_r     = al(o_esrc + (size_t)ne * 4);      // r = h@W2r, bf16 [nn,64]
    size_t o_xb    = al(o_r + (size_t)nn * 64 * 2);    // x as bf16
    size_t o_g     = al(o_xb + (size_t)nn * 64 * 2);   // g = h@W2l, bf16 [nn,64]
    size_t ws_req  = o_g + (size_t)nn * 64 * 2;

    // overlays inside the r region (all dead before layer1 writes r):
    size_t o_ep   = o_r;                               // ne*4 B
    size_t o_h2d  = al(o_ep + (size_t)ne * 4);         // nb*NCP*4
    size_t o_b2d  = al(o_h2d + (size_t)512 * NCP * 4); // nb*NCP*4
    size_t ov_end = o_b2d + (size_t)512 * NCP * 4;

    bool ok = ws_size >= ws_req && nb >= 1 && nb <= 512 && nn <= 131072 &&
              nchunk <= NCP && ov_end <= o_xb;
    if (!ok) {
        zero_out_k<<<(out_size + 255) / 256, 256, 0, stream>>>((u16*)d_out, out_size);
        return;
    }

    char* ws = (char*)d_ws;
    int* flags  = (int*)(ws + o_flags);
    int* btot   = (int*)(ws + o_btot);
    u16* wpk    = (u16*)(ws + o_wpk);
    int* cnt    = (int*)(ws + o_cnt);
    int* off    = (int*)(ws + o_off);
    int* esrc   = (int*)(ws + o_esrc);
    u16* rbuf   = (u16*)(ws + o_r);
    u16* xb     = (u16*)(ws + o_xb);
    u16* gbuf   = (u16*)(ws + o_g);
    unsigned* ep = (unsigned*)(ws + o_ep);
    int* hist2d = (int*)(ws + o_h2d);
    int* base2d = (int*)(ws + o_b2d);

    int ncvt = (nn * 16 + 511) / 512;
    setup_k<<<nchunk + ncvt + 5, 512, 0, stream>>>(
        x, ei, W1l, W1r, b1, W2l, W2r, b2, wpk, xb, hist2d, flags,
        nn, ne, nb, nchunk, ncvt,
        in_sizes[0], in_sizes[2], in_sizes[3], in_sizes[4],
        in_sizes[5], in_sizes[6], in_sizes[7]);
    scan2d<<<nb, 256, 0, stream>>>(hist2d, base2d, btot, nchunk);
    partition_k<<<nchunk, 512, 0, stream>>>(ei, btot, base2d, ep, nn, ne, nb);
    csr_fill2<<<nb, 512, 0, stream>>>(ep, btot, off, cnt, esrc, nn, nb);
    int lb = (nn + 31) / 32;
    layer1<<<lb, 512, 0, stream>>>(x, xb, esrc, off, cnt,
                                   wpk, wpk + 16384, wpk + 24576, b1,
                                   gbuf, rbuf, flags, nn);
    layer2<<<lb, 512, 0, stream>>>(gbuf, rbuf, esrc, off, cnt, b2, d_out, flags, nn);
}